// Round 3
// baseline (17230.467 us; speedup 1.0000x reference)
//
#include <hip/hip_runtime.h>
#include <hip/hip_bf16.h>

// Problem constants
#define B_  2048   // batch
#define T_  32     // T_SRC == T_TGT
#define D_  512    // model dim
#define G_  2048   // 4*D
#define VT_ 80     // D_TGT (decoder vocab / logit dim)

static __device__ __forceinline__ float sigm(float x) {
    return 1.0f / (1.0f + expf(-x));
}

// ---------------------------------------------------------------------------
// init: zero the 6 fp32 state planes (4 h ping-pong + 2 c; ws re-poisoned to
// 0xAA before every launch) and set pred[b] = tgt[b, 0].
// ---------------------------------------------------------------------------
__global__ void init_state(float* __restrict__ planes, int n,
                           const int* __restrict__ tgt, int* __restrict__ pred) {
    int i = blockIdx.x * blockDim.x + threadIdx.x;
    if (i < n) planes[i] = 0.0f;
    if (i < B_) pred[i] = tgt[i * T_];   // tgt[b][0]
}

// ---------------------------------------------------------------------------
// Fused LSTM cell (all fp32): for a 128(M) x 16(d) tile, compute the four
// gate columns n = d + {0,512,1024,1536} with full K=512 sums over both
// x@Wih^T and h@Whh^T, add biases, apply the LSTM nonlinearity, write
// h_out / c (c strictly in place by owning thread; h double-buffered).
//
// B-tile column c in [0,64): gate j = c & 3, d = d0 + (c >> 2),
// global weight row n = d0 + (c>>2) + (c&3)*512. Thread (ty,tx) microtile:
// 8 m-rows x [4 gates of d = d0 + tx] -> epilogue self-contained.
// ---------------------------------------------------------------------------
__global__ __launch_bounds__(256) void lstm_cell_fused(
    const float* __restrict__ xf,               // fp32 x (B x D) or nullptr
    const float* __restrict__ emb,              // fp32 gather table if xf==nullptr
    const int* __restrict__ idx, int idx_stride, int emb_rows,
    const float* __restrict__ hin,              // fp32 h in  (B x D)
    float* __restrict__ hout,                   // fp32 h out (B x D)
    float* __restrict__ cio,                    // fp32 c in/out (B x D)
    const float* __restrict__ Wih,              // (G x D)
    const float* __restrict__ Whh,              // (G x D)
    const float* __restrict__ bih,              // (G)
    const float* __restrict__ bhh)              // (G)
{
    __shared__ float As[16][128];
    __shared__ float Bs[16][64];

    const int tid = threadIdx.x;
    const int d0 = blockIdx.x * 16;
    const int m0 = blockIdx.y * 128;

    const int a_m = tid & 127;           // A-load row within tile
    const int a_k = (tid >> 7) * 8;      // A-load k offset (0 or 8), 8 elems
    const int b_c = tid & 63;            // B-tile storage column
    const int b_k = (tid >> 6) * 4;      // B-load k offset (0/4/8/12), 4 elems
    const int b_n = d0 + (b_c >> 2) + (b_c & 3) * D_;  // global gate row

    const int ty = tid >> 4;             // 0..15 -> rows ty*8 .. +8
    const int tx = tid & 15;             // 0..15 -> d = d0 + tx

    float acc[8][4];
    #pragma unroll
    for (int i = 0; i < 8; ++i)
        #pragma unroll
        for (int j = 0; j < 4; ++j) acc[i][j] = 0.0f;

    const int am_g = m0 + a_m;
    const float* arow;                   // phase-0 A row (x)
    if (xf) {
        arow = xf + (size_t)am_g * D_;
    } else {
        int r = idx[am_g * idx_stride];
        if (r < 0) r = 0;
        if (r >= emb_rows) r = emb_rows - 1;   // defensive: no wild gathers
        arow = emb + (size_t)r * D_;
    }
    const float* hrow = hin + (size_t)am_g * D_;

    for (int phase = 0; phase < 2; ++phase) {
        const float* Arow = (phase == 0) ? arow : hrow;
        const float* wrow = ((phase == 0) ? Wih : Whh) + (size_t)b_n * D_ + b_k;

        for (int kt = 0; kt < D_; kt += 16) {
            // ---- stage A tile (As[k][m]), 8 floats per thread ----
            {
                const float4* p = (const float4*)(Arow + kt + a_k);
                float4 v0 = p[0], v1 = p[1];
                As[a_k + 0][a_m] = v0.x; As[a_k + 1][a_m] = v0.y;
                As[a_k + 2][a_m] = v0.z; As[a_k + 3][a_m] = v0.w;
                As[a_k + 4][a_m] = v1.x; As[a_k + 5][a_m] = v1.y;
                As[a_k + 6][a_m] = v1.z; As[a_k + 7][a_m] = v1.w;
            }
            // ---- stage B tile (Bs[k][c]), 4 floats per thread ----
            {
                float4 w = *(const float4*)(wrow + kt);
                Bs[b_k + 0][b_c] = w.x;
                Bs[b_k + 1][b_c] = w.y;
                Bs[b_k + 2][b_c] = w.z;
                Bs[b_k + 3][b_c] = w.w;
            }
            __syncthreads();

            #pragma unroll
            for (int kk = 0; kk < 16; ++kk) {
                const float4* ap = (const float4*)&As[kk][ty * 8];
                float4 a0 = ap[0], a1 = ap[1];
                float4 b0 = *(const float4*)&Bs[kk][tx * 4];
                float a[8] = {a0.x, a0.y, a0.z, a0.w, a1.x, a1.y, a1.z, a1.w};
                float b[4] = {b0.x, b0.y, b0.z, b0.w};
                #pragma unroll
                for (int i = 0; i < 8; ++i)
                    #pragma unroll
                    for (int j = 0; j < 4; ++j)
                        acc[i][j] += a[i] * b[j];
            }
            __syncthreads();
        }
    }

    // ---- fused LSTM epilogue ----
    const int d = d0 + tx;
    float bias[4];
    #pragma unroll
    for (int j = 0; j < 4; ++j) {
        int n = d + j * D_;
        bias[j] = bih[n] + bhh[n];
    }
    #pragma unroll
    for (int i = 0; i < 8; ++i) {
        int m = m0 + ty * 8 + i;
        size_t off = (size_t)m * D_ + d;
        float gi = acc[i][0] + bias[0];
        float gf = acc[i][1] + bias[1];
        float gg = acc[i][2] + bias[2];
        float go = acc[i][3] + bias[3];
        float cold = cio[off];
        float cn = sigm(gf) * cold + sigm(gi) * tanhf(gg);
        float hn = sigm(go) * tanhf(cn);
        cio[off]  = cn;
        hout[off] = hn;
    }
}

// ---------------------------------------------------------------------------
// logits[b,v] = h1[b,:] . post_W[v,:] + post_b[v]; first-max argmax -> pred;
// logits stored fp32 to out[b, t, :]. One block per batch row.
// ---------------------------------------------------------------------------
__global__ __launch_bounds__(128) void logits_argmax(
    const float* __restrict__ h1,                 // (B x D)
    const float* __restrict__ postW,              // (VT x D)
    const float* __restrict__ postb,              // (VT)
    float* __restrict__ out,                      // (B x T x VT)
    int t,
    int* __restrict__ pred) {
    __shared__ float hs[D_];
    __shared__ float lg[VT_];
    int b = blockIdx.x;
    int tid = threadIdx.x;

    ((float4*)hs)[tid] = ((const float4*)(h1 + (size_t)b * D_))[tid];
    __syncthreads();

    if (tid < VT_) {
        const float* wr = postW + (size_t)tid * D_;
        float acc = 0.0f;
        for (int d0 = 0; d0 < D_; d0 += 4) {
            float4 w = *(const float4*)(wr + d0);
            acc += hs[d0 + 0] * w.x + hs[d0 + 1] * w.y
                 + hs[d0 + 2] * w.z + hs[d0 + 3] * w.w;
        }
        acc += postb[tid];
        lg[tid] = acc;
    }
    __syncthreads();
    if (tid == 0) {
        float best = lg[0]; int bi = 0;
        for (int v = 1; v < VT_; ++v) {
            float x = lg[v];
            if (x > best) { best = x; bi = v; }
        }
        pred[b] = bi;
    }
    if (tid < VT_) {
        out[(size_t)b * (T_ * VT_) + (size_t)t * VT_ + tid] = lg[tid];
    }
}

// ---------------------------------------------------------------------------
extern "C" void kernel_launch(void* const* d_in, const int* in_sizes, int n_in,
                              void* d_out, int out_size, void* d_ws, size_t ws_size,
                              hipStream_t stream) {
    (void)in_sizes; (void)n_in; (void)out_size; (void)ws_size;

    const int*   src     = (const int*)d_in[0];
    const int*   tgt     = (const int*)d_in[1];
    const float* enc_emb = (const float*)d_in[2];    // (100, D)
    const float* dec_emb = (const float*)d_in[3];    // (80, D)
    const float* enc_Wih = (const float*)d_in[4];    // (2, G, D)
    const float* enc_Whh = (const float*)d_in[5];
    const float* enc_bih = (const float*)d_in[6];    // (2, G)
    const float* enc_bhh = (const float*)d_in[7];
    const float* dec_Wih = (const float*)d_in[8];
    const float* dec_Whh = (const float*)d_in[9];
    const float* dec_bih = (const float*)d_in[10];
    const float* dec_bhh = (const float*)d_in[11];
    const float* post_W  = (const float*)d_in[12];   // (80, D)
    const float* post_b  = (const float*)d_in[13];   // (80)

    const size_t LW = (size_t)G_ * D_;   // per-layer weight elems
    const size_t PL = (size_t)B_ * D_;   // per-layer state plane elems

    // ws layout (16 KiB + 24 MiB total):
    //   [0)      pred: B_ int32 (8 KiB, padded to 16 KiB)
    //   [16KiB)  6 fp32 planes: h0 ping/pong, h1 ping/pong, c0, c1
    int*   pred   = (int*)d_ws;
    float* planes = (float*)d_ws + 4096;
    float* H[2][2] = { { planes,          planes + PL     },
                       { planes + 2 * PL, planes + 3 * PL } };
    float* C[2]    = {   planes + 4 * PL, planes + 5 * PL };

    float* out = (float*)d_out;

    {
        int n = (int)(6 * PL);
        init_state<<<(n + 255) / 256, 256, 0, stream>>>(planes, n, tgt, pred);
    }

    dim3 grid(D_ / 16, B_ / 128);        // (32, 16)
    int c0 = 0, c1 = 0;                   // current h slot per layer

    // -------- encoder --------
    for (int t = 0; t < T_; ++t) {
        lstm_cell_fused<<<grid, 256, 0, stream>>>(
            nullptr, enc_emb, src + t, T_, 100,
            H[0][c0], H[0][c0 ^ 1], C[0],
            enc_Wih, enc_Whh, enc_bih, enc_bhh);
        c0 ^= 1;
        lstm_cell_fused<<<grid, 256, 0, stream>>>(
            H[0][c0], nullptr, nullptr, 0, 0,
            H[1][c1], H[1][c1 ^ 1], C[1],
            enc_Wih + LW, enc_Whh + LW, enc_bih + G_, enc_bhh + G_);
        c1 ^= 1;
    }

    // -------- decoder (greedy feedback) --------
    for (int t = 0; t < T_; ++t) {
        lstm_cell_fused<<<grid, 256, 0, stream>>>(
            nullptr, dec_emb, pred, 1, VT_,
            H[0][c0], H[0][c0 ^ 1], C[0],
            dec_Wih, dec_Whh, dec_bih, dec_bhh);
        c0 ^= 1;
        lstm_cell_fused<<<grid, 256, 0, stream>>>(
            H[0][c0], nullptr, nullptr, 0, 0,
            H[1][c1], H[1][c1 ^ 1], C[1],
            dec_Wih + LW, dec_Whh + LW, dec_bih + G_, dec_bhh + G_);
        c1 ^= 1;
        logits_argmax<<<B_, 128, 0, stream>>>(
            H[1][c1], post_W, post_b, out, t, pred);
    }
}

// Round 4
// 6128.802 us; speedup vs baseline: 2.8114x; 2.8114x over previous
//
#include <hip/hip_runtime.h>
#include <hip/hip_bf16.h>

// Problem constants
#define B_  2048   // batch
#define T_  32     // T_SRC == T_TGT
#define D_  512    // model dim
#define G_  2048   // 4*D
#define VT_ 80     // D_TGT
#define BD  (B_ * D_)          // 1048576 elems per state plane
#define LWE ((size_t)G_ * D_)  // per-layer weight elems (1048576)

typedef _Float16 half8 __attribute__((ext_vector_type(8)));
typedef float    f32x4 __attribute__((ext_vector_type(4)));

static __device__ __forceinline__ float sigm(float x) {
    return 1.0f / (1.0f + expf(-x));
}

// async global->LDS, 16 B per lane; LDS dest = wave-uniform base + lane*16,
// global src is per-lane (gather allowed).
#define GLD16(gp, lp)                                                         \
    __builtin_amdgcn_global_load_lds(                                         \
        (const __attribute__((address_space(1))) void*)(gp),                  \
        (__attribute__((address_space(3))) void*)(lp), 16, 0, 0)

// ---------------------------------------------------------------------------
// zero 16 MiB state span (c planes + slot-0 h_hi/h_lo planes)
// ---------------------------------------------------------------------------
__global__ void zero_ws(int4* __restrict__ p, int n) {
    int i = blockIdx.x * blockDim.x + threadIdx.x;
    if (i < n) p[i] = int4{0, 0, 0, 0};
}
__global__ void init_pred(const int* __restrict__ tgt, int* __restrict__ pred) {
    int i = blockIdx.x * blockDim.x + threadIdx.x;
    if (i < B_) pred[i] = tgt[i * T_];
}

// ---------------------------------------------------------------------------
// Split 6 weight matrices (fp32 GxD) into fp16 hi/lo planes, stored with
// gate-interleaved column order n' = d*4 + g  (orig row n = g*512 + d) and
// MFMA B-fragment tile order: tile(NI=n'>>4, KC=k>>5) of 64 lanes x 8 elems,
// lane = (n'&15) | (((k>>3)&3)<<4), elem j = k&7.
// ---------------------------------------------------------------------------
__global__ void split_weights(const float* __restrict__ s0, const float* __restrict__ s1,
                              const float* __restrict__ s2, const float* __restrict__ s3,
                              const float* __restrict__ s4, const float* __restrict__ s5,
                              _Float16* __restrict__ Wbase) {
    int g = blockIdx.x * blockDim.x + threadIdx.x;   // 6 * 2048 * 64
    int mat = g >> 17;                                // /(2048*64)
    int rem = g & 131071;
    int np  = rem >> 6;                               // n' 0..2047
    int kq  = rem & 63;                               // k-octet 0..63
    const float* src = (mat == 0) ? s0 : (mat == 1) ? s1 : (mat == 2) ? s2
                     : (mat == 3) ? s3 : (mat == 4) ? s4 : s5;
    int n = (np & 3) * D_ + (np >> 2);
    const float* sp = src + (size_t)n * D_ + kq * 8;
    float4 v0 = ((const float4*)sp)[0], v1 = ((const float4*)sp)[1];
    float x[8] = {v0.x, v0.y, v0.z, v0.w, v1.x, v1.y, v1.z, v1.w};
    _Float16 hi[8], lo[8];
    #pragma unroll
    for (int u = 0; u < 8; ++u) {
        hi[u] = (_Float16)x[u];
        lo[u] = (_Float16)(x[u] - (float)hi[u]);
    }
    int tile = (np >> 4) * 16 + (kq >> 2);
    int lane = (np & 15) | ((kq & 3) << 4);
    size_t e = (size_t)tile * 512 + (size_t)lane * 8;
    _Float16* Whi = Wbase + (size_t)mat * (2 * LWE);
    _Float16* Wlo = Whi + LWE;
    *(half8*)(Whi + e) = *(half8*)hi;
    *(half8*)(Wlo + e) = *(half8*)lo;
}

// ---------------------------------------------------------------------------
// biasP[cfg][n'] = bih[n] + bhh[n], cfg: 0=enc l0, 1=enc l1, 2=dec l0, 3=dec l1
// ---------------------------------------------------------------------------
__global__ void perm_bias(const float* __restrict__ ebih, const float* __restrict__ ebhh,
                          const float* __restrict__ dbih, const float* __restrict__ dbhh,
                          float* __restrict__ biasP) {
    int i = blockIdx.x * blockDim.x + threadIdx.x;   // 0..8191
    int cfg = i >> 11, np = i & 2047;
    int n = (np & 3) * D_ + (np >> 2);
    const float* bi = ((cfg < 2) ? ebih : dbih) + (cfg & 1) * G_;
    const float* bh = ((cfg < 2) ? ebhh : dbhh) + (cfg & 1) * G_;
    biasP[cfg * G_ + np] = bi[n] + bh[n];
}

// ---------------------------------------------------------------------------
// Exact fp32 input projections: P[row][n'] = emb[s] . Wih0[n], permuted n'.
// rows 0..99 = enc, 100..179 = dec.
// ---------------------------------------------------------------------------
__global__ __launch_bounds__(256) void compute_P(
    const float* __restrict__ enc_emb, const float* __restrict__ dec_emb,
    const float* __restrict__ encW0,   const float* __restrict__ decW0,
    float* __restrict__ P) {
    __shared__ float es[D_];
    int row = blockIdx.y;
    const float* emb; const float* W; int s;
    if (row < 100) { emb = enc_emb; W = encW0; s = row; }
    else           { emb = dec_emb; W = decW0; s = row - 100; }
    ((float2*)es)[threadIdx.x] = ((const float2*)(emb + (size_t)s * D_))[threadIdx.x];
    __syncthreads();
    int np = blockIdx.x * 256 + threadIdx.x;
    int n = (np & 3) * D_ + (np >> 2);
    const float* wr = W + (size_t)n * D_;
    float acc = 0.0f;
    for (int k = 0; k < D_; k += 4) {
        float4 w4 = *(const float4*)(wr + k);
        acc += es[k] * w4.x + es[k+1] * w4.y + es[k+2] * w4.z + es[k+3] * w4.w;
    }
    P[(size_t)row * G_ + np] = acc;
}

// ---------------------------------------------------------------------------
// MFMA LSTM cell. Tile: BM=128 (blockIdx.y), BN=64 n' (blockIdx.x), BK=32.
// fp16 hi/lo split, 4 cross products into one fp32 accumulator.
// Phase 0/1: gates += A_ph @ W_ph'^T. Epilogue: +bias' (+P gather for layer 0),
// LSTM nonlinearity, write h_hi/h_lo fp16, c fp32 in place, optional h fp32.
// ---------------------------------------------------------------------------
__global__ __launch_bounds__(256) void lstm_cell_mfma(
    const _Float16* __restrict__ a0h, const _Float16* __restrict__ a0l,
    const _Float16* __restrict__ w0h, const _Float16* __restrict__ w0l,
    const _Float16* __restrict__ a1h, const _Float16* __restrict__ a1l,
    const _Float16* __restrict__ w1h, const _Float16* __restrict__ w1l,
    int nph,
    const float* __restrict__ biasP,   // 2048 fp32, permuted (cfg slice)
    const float* __restrict__ P,       // permuted rows, or nullptr (layer 1)
    const int* __restrict__ idx, int idx_stride, int emb_rows,
    float* __restrict__ c_io,
    _Float16* __restrict__ hh_out, _Float16* __restrict__ hl_out,
    float* __restrict__ hf_out) {
    __shared__ char smem[36864];   // staging 24 KB | epilogue gates 34 KB
    const int tid  = threadIdx.x;
    const int w    = tid >> 6;
    const int lane = tid & 63;
    const int bx = blockIdx.x;
    const int m0 = blockIdx.y * 128;
    const int mw = w & 1, nw = w >> 1;

    f32x4 acc[4][2];
    #pragma unroll
    for (int i = 0; i < 4; ++i)
        #pragma unroll
        for (int j = 0; j < 2; ++j) acc[i][j] = f32x4{0.f, 0.f, 0.f, 0.f};

    for (int ph = 0; ph < nph; ++ph) {
        const _Float16* Ah = ph ? a1h : a0h;
        const _Float16* Al = ph ? a1l : a0l;
        const _Float16* Wh = ph ? w1h : w0h;
        const _Float16* Wl = ph ? w1l : w0l;
        for (int kc = 0; kc < 16; ++kc) {
            const int kt = kc << 5;
            // ---- stage: 6 global_load_lds per wave ----
            {
                int mi = 2 * w;
                int mg = m0 + (mi << 4) + (lane & 15);
                int kg = kt + ((lane >> 4) << 3);
                size_t ga = (size_t)mg * D_ + kg;
                GLD16(Ah + ga, smem + ((0 * 8 + mi) << 10));
                GLD16(Al + ga, smem + ((1 * 8 + mi) << 10));
                ga += (size_t)16 * D_;
                GLD16(Ah + ga, smem + ((0 * 8 + mi + 1) << 10));
                GLD16(Al + ga, smem + ((1 * 8 + mi + 1) << 10));
                int tile = (bx * 4 + w) * 16 + kc;
                size_t wa = (size_t)tile * 512 + (size_t)lane * 8;
                GLD16(Wh + wa, smem + 16384 + ((0 * 4 + w) << 10));
                GLD16(Wl + wa, smem + 16384 + ((1 * 4 + w) << 10));
            }
            __syncthreads();
            half8 a[2][4], b[2][2];
            #pragma unroll
            for (int p = 0; p < 2; ++p) {
                #pragma unroll
                for (int i = 0; i < 4; ++i)
                    a[p][i] = ((const half8*)(smem + ((p * 8 + mw * 4 + i) << 10)))[lane];
                #pragma unroll
                for (int j = 0; j < 2; ++j)
                    b[p][j] = ((const half8*)(smem + 16384 + ((p * 4 + nw * 2 + j) << 10)))[lane];
            }
            #pragma unroll
            for (int i = 0; i < 4; ++i)
                #pragma unroll
                for (int j = 0; j < 2; ++j) {
                    acc[i][j] = __builtin_amdgcn_mfma_f32_16x16x32_f16(a[0][i], b[0][j], acc[i][j], 0, 0, 0);
                    acc[i][j] = __builtin_amdgcn_mfma_f32_16x16x32_f16(a[0][i], b[1][j], acc[i][j], 0, 0, 0);
                    acc[i][j] = __builtin_amdgcn_mfma_f32_16x16x32_f16(a[1][i], b[0][j], acc[i][j], 0, 0, 0);
                    acc[i][j] = __builtin_amdgcn_mfma_f32_16x16x32_f16(a[1][i], b[1][j], acc[i][j], 0, 0, 0);
                }
            __syncthreads();
        }
    }

    // ---- epilogue: gates -> LDS (row-pad 68 floats to break bank aliasing) ----
    float* gf = (float*)smem;
    {
        int rbase = (lane >> 4) << 2;       // C/D: row = quad*4 + reg (m)
        int cbase = lane & 15;              //      col = lane&15      (n')
        #pragma unroll
        for (int i = 0; i < 4; ++i)
            #pragma unroll
            for (int j = 0; j < 2; ++j) {
                int ml = (mw * 4 + i) * 16 + rbase;
                int nl = (nw * 2 + j) * 16 + cbase;
                #pragma unroll
                for (int r = 0; r < 4; ++r)
                    gf[(ml + r) * 68 + nl] = acc[i][j][r];
            }
    }
    __syncthreads();
    {
        int ml  = tid >> 1;
        int d0l = (tid & 1) << 3;
        int mg  = m0 + ml;
        int dg0 = (bx << 4) + d0l;
        const float* Prow = nullptr;
        if (P) {
            int s = idx[mg * idx_stride];
            s = min(max(s, 0), emb_rows - 1);
            Prow = P + (size_t)s * G_ + (bx << 6) + (d0l << 2);
        }
        const float* brow = biasP + (bx << 6) + (d0l << 2);
        float* crow = c_io + (size_t)mg * D_ + dg0;
        float cv[8], hv[8];
        *(float4*)&cv[0] = ((const float4*)crow)[0];
        *(float4*)&cv[4] = ((const float4*)crow)[1];
        _Float16 hh[8], hl[8];
        #pragma unroll
        for (int e = 0; e < 8; ++e) {
            float4 g4 = *(float4*)&gf[ml * 68 + (d0l + e) * 4];
            float4 b4 = *(const float4*)(brow + e * 4);
            float gi = g4.x + b4.x, gF = g4.y + b4.y;
            float gg = g4.z + b4.z, go = g4.w + b4.w;
            if (Prow) {
                float4 p4 = *(const float4*)(Prow + e * 4);
                gi += p4.x; gF += p4.y; gg += p4.z; go += p4.w;
            }
            float cn = sigm(gF) * cv[e] + sigm(gi) * tanhf(gg);
            float hn = sigm(go) * tanhf(cn);
            cv[e] = cn; hv[e] = hn;
            _Float16 h_ = (_Float16)hn;
            hh[e] = h_;
            hl[e] = (_Float16)(hn - (float)h_);
        }
        ((float4*)crow)[0] = *(float4*)&cv[0];
        ((float4*)crow)[1] = *(float4*)&cv[4];
        *(half8*)(hh_out + (size_t)mg * D_ + dg0) = *(half8*)hh;
        *(half8*)(hl_out + (size_t)mg * D_ + dg0) = *(half8*)hl;
        if (hf_out) {
            float* hrow = hf_out + (size_t)mg * D_ + dg0;
            ((float4*)hrow)[0] = *(float4*)&hv[0];
            ((float4*)hrow)[1] = *(float4*)&hv[4];
        }
    }
}

// ---------------------------------------------------------------------------
// logits (exact fp32) + first-max argmax -> pred; store fp32 out[b,t,:].
// ---------------------------------------------------------------------------
__global__ __launch_bounds__(128) void logits_argmax(
    const float* __restrict__ h1, const float* __restrict__ postW,
    const float* __restrict__ postb, float* __restrict__ out,
    int t, int* __restrict__ pred) {
    __shared__ float hs[D_];
    __shared__ float lg[VT_];
    int b = blockIdx.x;
    int tid = threadIdx.x;
    ((float4*)hs)[tid] = ((const float4*)(h1 + (size_t)b * D_))[tid];
    __syncthreads();
    if (tid < VT_) {
        const float* wr = postW + (size_t)tid * D_;
        float acc = 0.0f;
        for (int d0 = 0; d0 < D_; d0 += 4) {
            float4 w4 = *(const float4*)(wr + d0);
            acc += hs[d0] * w4.x + hs[d0+1] * w4.y + hs[d0+2] * w4.z + hs[d0+3] * w4.w;
        }
        lg[tid] = acc + postb[tid];
    }
    __syncthreads();
    if (tid == 0) {
        float best = lg[0]; int bi = 0;
        for (int v = 1; v < VT_; ++v) { float x = lg[v]; if (x > best) { best = x; bi = v; } }
        pred[b] = bi;
    }
    if (tid < VT_)
        out[(size_t)b * (T_ * VT_) + (size_t)t * VT_ + tid] = lg[tid];
}

// ---------------------------------------------------------------------------
extern "C" void kernel_launch(void* const* d_in, const int* in_sizes, int n_in,
                              void* d_out, int out_size, void* d_ws, size_t ws_size,
                              hipStream_t stream) {
    (void)in_sizes; (void)n_in; (void)out_size; (void)ws_size;

    const int*   src     = (const int*)d_in[0];
    const int*   tgt     = (const int*)d_in[1];
    const float* enc_emb = (const float*)d_in[2];
    const float* dec_emb = (const float*)d_in[3];
    const float* enc_Wih = (const float*)d_in[4];
    const float* enc_Whh = (const float*)d_in[5];
    const float* enc_bih = (const float*)d_in[6];
    const float* enc_bhh = (const float*)d_in[7];
    const float* dec_Wih = (const float*)d_in[8];
    const float* dec_Whh = (const float*)d_in[9];
    const float* dec_bih = (const float*)d_in[10];
    const float* dec_bhh = (const float*)d_in[11];
    const float* post_W  = (const float*)d_in[12];
    const float* post_b  = (const float*)d_in[13];

    // ---- ws layout (~56 MiB) ----
    char* wsb = (char*)d_ws;
    int*   pred  = (int*)wsb;                                   // 16 KB
    float* biasB = (float*)(wsb + 16384);                       // 32 KB
    float* Ptab  = (float*)(wsb + 16384 + 32768);               // 180*2048*4 = 1.41 MiB
    char*  zbase = wsb + 16384 + 32768 + 180 * G_ * 4;          // zero-span start
    float* C0 = (float*)zbase;             // c planes, fp32
    float* C1 = C0 + BD;
    _Float16* Hh00 = (_Float16*)(C1 + BD); // slot-0 h planes (zeroed)
    _Float16* Hh10 = Hh00 + BD;
    _Float16* Hl00 = Hh10 + BD;
    _Float16* Hl10 = Hl00 + BD;
    _Float16* Hh01 = Hl10 + BD;            // slot-1 h planes
    _Float16* Hh11 = Hh01 + BD;
    _Float16* Hl01 = Hh11 + BD;
    _Float16* Hl11 = Hl01 + BD;
    float*    HF   = (float*)(Hl11 + BD);  // layer-1 h fp32 (for logits)
    _Float16* Wb   = (_Float16*)(HF + BD); // 6 split matrices, 24 MiB

    _Float16* Hhi[2][2] = { { Hh00, Hh01 }, { Hh10, Hh11 } };
    _Float16* Hlo[2][2] = { { Hl00, Hl01 }, { Hl10, Hl11 } };
    float*    Cp[2]     = { C0, C1 };
    // matrices: 0 encWhh0, 1 encWih1, 2 encWhh1, 3 decWhh0, 4 decWih1, 5 decWhh1
    auto WP = [&](int m, int pl) { return Wb + (size_t)m * (2 * LWE) + (size_t)pl * LWE; };

    float* out = (float*)d_out;

    // ---- precompute ----
    zero_ws<<<4096, 256, 0, stream>>>((int4*)zbase, (16 * 1024 * 1024) / 16);
    init_pred<<<8, 256, 0, stream>>>(tgt, pred);
    split_weights<<<3072, 256, 0, stream>>>(
        enc_Whh, enc_Wih + LWE, enc_Whh + LWE,
        dec_Whh, dec_Wih + LWE, dec_Whh + LWE, Wb);
    perm_bias<<<32, 256, 0, stream>>>(enc_bih, enc_bhh, dec_bih, dec_bhh, biasB);
    {
        dim3 g(8, 180);
        compute_P<<<g, 256, 0, stream>>>(enc_emb, dec_emb, enc_Wih, dec_Wih, Ptab);
    }

    dim3 grid(G_ / 64, B_ / 128);    // (32, 16)
    int c0 = 0, c1 = 0;

    // -------- encoder --------
    for (int t = 0; t < T_; ++t) {
        lstm_cell_mfma<<<grid, 256, 0, stream>>>(
            Hhi[0][c0], Hlo[0][c0], WP(0, 0), WP(0, 1),
            nullptr, nullptr, nullptr, nullptr, 1,
            biasB + 0 * G_, Ptab, src + t, T_, 100,
            Cp[0], Hhi[0][c0 ^ 1], Hlo[0][c0 ^ 1], nullptr);
        c0 ^= 1;
        lstm_cell_mfma<<<grid, 256, 0, stream>>>(
            Hhi[0][c0], Hlo[0][c0], WP(1, 0), WP(1, 1),
            Hhi[1][c1], Hlo[1][c1], WP(2, 0), WP(2, 1), 2,
            biasB + 1 * G_, nullptr, nullptr, 0, 0,
            Cp[1], Hhi[1][c1 ^ 1], Hlo[1][c1 ^ 1], nullptr);
        c1 ^= 1;
    }

    // -------- decoder (greedy feedback) --------
    for (int t = 0; t < T_; ++t) {
        lstm_cell_mfma<<<grid, 256, 0, stream>>>(
            Hhi[0][c0], Hlo[0][c0], WP(3, 0), WP(3, 1),
            nullptr, nullptr, nullptr, nullptr, 1,
            biasB + 2 * G_, Ptab + (size_t)100 * G_, pred, 1, VT_,
            Cp[0], Hhi[0][c0 ^ 1], Hlo[0][c0 ^ 1], nullptr);
        c0 ^= 1;
        lstm_cell_mfma<<<grid, 256, 0, stream>>>(
            Hhi[0][c0], Hlo[0][c0], WP(4, 0), WP(4, 1),
            Hhi[1][c1], Hlo[1][c1], WP(5, 0), WP(5, 1), 2,
            biasB + 3 * G_, nullptr, nullptr, 0, 0,
            Cp[1], Hhi[1][c1 ^ 1], Hlo[1][c1 ^ 1], HF);
        c1 ^= 1;
        logits_argmax<<<B_, 128, 0, stream>>>(HF, post_W, post_b, out, t, pred);
    }
}